// Round 4
// baseline (357.942 us; speedup 1.0000x reference)
//
#include <hip/hip_runtime.h>
#include <math.h>

#define INV_SQRT2F 0.7071067811865476f

#define GRID_BLOCKS   1024
#define BLOCK_THREADS 256
#define U_PER_THREAD  16                                  // float4 per thread per phase
#define BLOCK_F4      (BLOCK_THREADS * U_PER_THREAD)      // 4096 float4 = 64 KB span/block
// n4 = 4194304 = GRID_BLOCKS * BLOCK_F4 exactly.

// R3 post-mortem: d[64] spilled (VGPR_Count 64, WRITE_SIZE 15.5 MB scratch)
// -> 284 us. R4: no per-thread array at all; phase 2 reloads pred/targ
// (L3-resident after phase 1: 134 MB < 256 MB L3) and recomputes d.
// Also: previous layout gave each thread's in-flight loads an 8-MB pow2
// stride == 0 mod 4-MB XCD L2 -> all outstanding misses alias one L2 set +
// camp HBM channels (suspected cause of the 2.6 TB/s effective ceiling).
// New layout: block-contiguous 64-KB spans; a thread's loads stride 4 KB.

// ws float layout:
//   [0..1023]    s1 partials  (per-block slot, plain overwrite of poison)
//   [1024..2047] s2 partials
//   [2048..3071] erf partials
//   [3072]       barrier counter 1 (uint)  } 128-B memset-zeroed region,
//   [3104]       barrier counter 2 (uint)  } separate 128-B lines
#define S1_BASE 0
#define S2_BASE 1024
#define SE_BASE 2048
#define C_BASE  3072
#define C1_IDX  3072
#define C2_IDX  3104

// Co-residency for the barrier: __launch_bounds__(256,4) -> >=4 waves/EU ->
// 4 WG/CU * 256 CU = 1024 blocks resident; grid is exactly 1024. Manual
// device-scope barrier (no cooperative API — that hung under graph capture).

__device__ __forceinline__ float aload(const float* p) {
    return __hip_atomic_load(p, __ATOMIC_RELAXED, __HIP_MEMORY_SCOPE_AGENT);
}
__device__ __forceinline__ void astore(float* p, float v) {
    __hip_atomic_store(p, v, __ATOMIC_RELAXED, __HIP_MEMORY_SCOPE_AGENT);
}

__global__ void __launch_bounds__(BLOCK_THREADS, 4)
fused(const float4* __restrict__ pred4, const float4* __restrict__ targ4,
      int n, float* __restrict__ ws, float* __restrict__ out)
{
    const int lane = threadIdx.x & 63;
    const int wid  = threadIdx.x >> 6;
    const int base = blockIdx.x * BLOCK_F4 + threadIdx.x;   // float4 index
    unsigned int* c1 = (unsigned int*)&ws[C1_IDX];
    unsigned int* c2 = (unsigned int*)&ws[C2_IDX];

    // ---- Phase 1: sum d and d^2 (block-contiguous, 4-deep load clusters) ----
    float s1 = 0.f, s2 = 0.f;
#pragma unroll
    for (int c = 0; c < 4; ++c) {
        float4 p[4], t[4];
#pragma unroll
        for (int u = 0; u < 4; ++u) p[u] = pred4[base + (c * 4 + u) * BLOCK_THREADS];
#pragma unroll
        for (int u = 0; u < 4; ++u) t[u] = targ4[base + (c * 4 + u) * BLOCK_THREADS];
        __builtin_amdgcn_sched_barrier(0);   // 8 loads in flight before any use
#pragma unroll
        for (int u = 0; u < 4; ++u) {
            float d0 = fabsf(p[u].x - t[u].x);
            float d1 = fabsf(p[u].y - t[u].y);
            float d2 = fabsf(p[u].z - t[u].z);
            float d3 = fabsf(p[u].w - t[u].w);
            s1 += (d0 + d1) + (d2 + d3);
            s2 += (d0 * d0 + d1 * d1) + (d2 * d2 + d3 * d3);
        }
    }

    for (int off = 32; off > 0; off >>= 1) {
        s1 += __shfl_down(s1, off);
        s2 += __shfl_down(s2, off);
    }
    __shared__ float ls1[4], ls2[4];
    if (lane == 0) { ls1[wid] = s1; ls2[wid] = s2; }
    __syncthreads();
    if (threadIdx.x == 0) {
        astore(&ws[S1_BASE + blockIdx.x], (ls1[0] + ls1[1]) + (ls1[2] + ls1[3]));
        astore(&ws[S2_BASE + blockIdx.x], (ls2[0] + ls2[1]) + (ls2[2] + ls2[3]));
        __hip_atomic_fetch_add(c1, 1u, __ATOMIC_RELEASE, __HIP_MEMORY_SCOPE_AGENT);
        while (__hip_atomic_load(c1, __ATOMIC_ACQUIRE, __HIP_MEMORY_SCOPE_AGENT)
               < (unsigned)GRID_BLOCKS)
            __builtin_amdgcn_s_sleep(1);
    }
    __syncthreads();
    (void)__hip_atomic_load(c1, __ATOMIC_ACQUIRE, __HIP_MEMORY_SCOPE_AGENT);

    // ---- all threads gather the 1024 partials (4 agent loads each) ----
    float g1 = 0.f, g2 = 0.f;
#pragma unroll
    for (int q = 0; q < 4; ++q) {
        g1 += aload(&ws[S1_BASE + threadIdx.x + 256 * q]);
        g2 += aload(&ws[S2_BASE + threadIdx.x + 256 * q]);
    }
    for (int off = 32; off > 0; off >>= 1) {
        g1 += __shfl_down(g1, off);
        g2 += __shfl_down(g2, off);
    }
    __shared__ float gs1[4], gs2[4];
    if (lane == 0) { gs1[wid] = g1; gs2[wid] = g2; }
    __syncthreads();
    float sum_d  = (gs1[0] + gs1[1]) + (gs1[2] + gs1[3]);
    float sum_d2 = (gs2[0] + gs2[1]) + (gs2[2] + gs2[3]);

    float nf     = (float)n;
    float mean_d = sum_d / nf;
    float var    = (sum_d2 - sum_d * mean_d) / (nf - 1.0f);
    float kk     = INV_SQRT2F / var;

    // ---- Phase 2: reload (L3-warm), recompute d, accumulate erf ----
    float s = 0.f;
#pragma unroll
    for (int c = 0; c < 4; ++c) {
        float4 p[4], t[4];
#pragma unroll
        for (int u = 0; u < 4; ++u) p[u] = pred4[base + (c * 4 + u) * BLOCK_THREADS];
#pragma unroll
        for (int u = 0; u < 4; ++u) t[u] = targ4[base + (c * 4 + u) * BLOCK_THREADS];
        __builtin_amdgcn_sched_barrier(0);
#pragma unroll
        for (int u = 0; u < 4; ++u) {
            s += (erff(fabsf(p[u].x - t[u].x) * kk) + erff(fabsf(p[u].y - t[u].y) * kk))
               + (erff(fabsf(p[u].z - t[u].z) * kk) + erff(fabsf(p[u].w - t[u].w) * kk));
        }
    }

    for (int off = 32; off > 0; off >>= 1)
        s += __shfl_down(s, off);
    __shared__ float es[4];
    if (lane == 0) es[wid] = s;
    __syncthreads();
    if (threadIdx.x == 0) {
        astore(&ws[SE_BASE + blockIdx.x], (es[0] + es[1]) + (es[2] + es[3]));
        __hip_atomic_fetch_add(c2, 1u, __ATOMIC_RELEASE, __HIP_MEMORY_SCOPE_AGENT);
    }

    // ---- block 0 alone waits for erf partials, reduces, writes out ----
    if (blockIdx.x == 0) {
        if (threadIdx.x == 0) {
            while (__hip_atomic_load(c2, __ATOMIC_ACQUIRE, __HIP_MEMORY_SCOPE_AGENT)
                   < (unsigned)GRID_BLOCKS)
                __builtin_amdgcn_s_sleep(1);
        }
        __syncthreads();
        (void)__hip_atomic_load(c2, __ATOMIC_ACQUIRE, __HIP_MEMORY_SCOPE_AGENT);

        float se = 0.f;
#pragma unroll
        for (int q = 0; q < 4; ++q)
            se += aload(&ws[SE_BASE + threadIdx.x + 256 * q]);
        for (int off = 32; off > 0; off >>= 1)
            se += __shfl_down(se, off);
        __shared__ float fs[4];
        if (lane == 0) fs[wid] = se;
        __syncthreads();
        if (threadIdx.x == 0) {
            float sum_erf = (fs[0] + fs[1]) + (fs[2] + fs[3]);
            float p       = 1.0f - sum_erf / nf;          // p_correct
            float gamma   = -logf(p);
            float coef    = expf(gamma * logf(1.0f - p)); // (1-p)^gamma
            out[0] = coef * mean_d + logf(var + 1.0f);    // LOSS_WEIGHT = 1
        }
    }
}

extern "C" void kernel_launch(void* const* d_in, const int* in_sizes, int n_in,
                              void* d_out, int out_size, void* d_ws, size_t ws_size,
                              hipStream_t stream) {
    const float4* pred4 = (const float4*)d_in[0];
    const float4* targ4 = (const float4*)d_in[1];
    float* out = (float*)d_out;
    float* ws  = (float*)d_ws;
    int n = in_sizes[0];         // 16777216; n4 = 4194304 = 1024 * 4096

    // zero ONLY the barrier counters (partial slots are plain-overwritten)
    hipMemsetAsync((char*)d_ws + C_BASE * sizeof(float), 0, 256, stream);

    fused<<<GRID_BLOCKS, BLOCK_THREADS, 0, stream>>>(pred4, targ4, n, ws, out);
}